// Round 3
// baseline (191.863 us; speedup 1.0000x reference)
//
#include <hip/hip_runtime.h>
#include <hip/hip_fp16.h>

typedef unsigned int u32;
typedef unsigned short u16;
typedef _Float16 f16x8 __attribute__((ext_vector_type(8)));
typedef float f32x4 __attribute__((ext_vector_type(4)));

#define OUT_F 8192
#define IN_F 8192
#define TOKENS 256
#define N_GROUPS 524288
#define SPLITK 4
#define KSPAN (IN_F / SPLITK)   // 2048 weights (== bytes of wq per row-split)
#define KT (KSPAN / 64)         // 32 K-iterations
#define TSLICES 8               // lora k-slices in prep

// workspace layout
#define XB_OFF 0
#define T_OFF ((size_t)TOKENS * IN_F * 2)                  // 4 MiB
#define T_BYTES ((size_t)TSLICES * TOKENS * 16 * 4)        // 128 KiB
#define NF_OFF (T_OFF + T_BYTES)
#define PART_OFF (NF_OFF + (size_t)N_GROUPS * 2)           // +1 MiB
#define PART_BYTES ((size_t)SPLITK * TOKENS * OUT_F * 4)   // 32 MiB
#define WS_NEED (PART_OFF + PART_BYTES)

// direct global -> LDS DMA, 16B per lane. LDS dest must be lane-linear
// (wave-uniform base + lane*16) -- our A chunk slots are exactly tid-linear,
// swizzle is applied on the GLOBAL source address (m173 pattern).
#define GLOAD16(g, l)                                                        \
  __builtin_amdgcn_global_load_lds(                                          \
      (const __attribute__((address_space(1))) void*)(g),                    \
      (__attribute__((address_space(3))) void*)(l), 16, 0, 0)

// packed f16 multiply on bit-pattern: 4 weights dequant = 1 LUT read + 2 of these
__device__ __forceinline__ u32 hm2(u32 a, __half2 s) {
  return __builtin_bit_cast(u32, __hmul2(__builtin_bit_cast(__half2, a), s));
}

// ---------------------------------------------------------------------------
// prep: fused normcvt + lora-projection + x->f16.
// blocks [0,512): weight_norm dtype auto-detect (f16/bf16/f32 vote) -> f16 nf.
// blocks [512,640): R7 k-sliced lora: block = (token-group of 16, k-slice of
// 1024). la traffic drops 128 MB -> 16 MB (was: every token-block re-read
// 256 KB of la). t becomes TSLICES=8 partial slices, summed in finish.
// ---------------------------------------------------------------------------
__global__ __launch_bounds__(256) void prep(const void* __restrict__ wn,
                                            __half* __restrict__ nf,
                                            const float* __restrict__ x,
                                            const float* __restrict__ la,
                                            u16* __restrict__ xb,
                                            float* __restrict__ t) {
  int tid = threadIdx.x;
  if (blockIdx.x < 512) {
    __shared__ int votes[3];
    if (tid < 3) votes[tid] = 0;
    __syncthreads();
    const u16* pu = (const u16*)wn;
    const u32* pw = (const u32*)wn;
    int v16 = 0, vbf = 0, vf = 0;
    for (int i = tid; i < 2048; i += 256) {
      u16 u = pu[i];
      float h = __half2float(__builtin_bit_cast(__half, u));
      float b = __builtin_bit_cast(float, ((u32)u) << 16);
      if (h > 0.008f && h < 1.002f) v16++;
      if (b > 0.008f && b < 1.002f) vbf++;
    }
    for (int i = tid; i < 1024; i += 256) {
      float f = __builtin_bit_cast(float, pw[i]);
      if (f > 0.008f && f < 1.002f) vf++;
    }
    atomicAdd(&votes[0], v16);
    atomicAdd(&votes[1], vbf);
    atomicAdd(&votes[2], vf);
    __syncthreads();
    int a16 = votes[0], abf = votes[1], af32 = 2 * votes[2];
    int mode = (a16 >= abf && a16 >= af32) ? 0 : (abf >= af32 ? 1 : 2);
#pragma unroll
    for (int i = 0; i < 4; ++i) {
      int g = blockIdx.x * 1024 + i * 256 + tid;
      float v;
      if (mode == 0) v = __half2float(((const __half*)wn)[g]);
      else if (mode == 1) v = __builtin_bit_cast(float, ((u32)((const u16*)wn)[g]) << 16);
      else v = ((const float*)wn)[g];
      nf[g] = __float2half(v);
    }
    return;
  }
  // lora/xb part: 128 blocks = 16 token-groups x 8 k-slices.
  int b2 = blockIdx.x - 512;
  int kq = b2 & 7;        // k-slice (1024 floats = 256 float4)
  int mg = b2 >> 3;       // token group
  int tm = tid >> 4, tk = tid & 15;
  int m = mg * 16 + tm;
  const float4* xr = (const float4*)(x + (size_t)m * IN_F);
  u32* xbr = (u32*)(xb + (size_t)m * IN_F);
  float pl[16];
#pragma unroll
  for (int r = 0; r < 16; ++r) pl[r] = 0.f;
#pragma unroll
  for (int it = 0; it < 16; ++it) {
    int k4 = kq * 256 + it * 16 + tk;
    float4 xv = xr[k4];
    u32 p0 = __builtin_bit_cast(u32, __float22half2_rn(make_float2(xv.x, xv.y)));
    u32 p1 = __builtin_bit_cast(u32, __float22half2_rn(make_float2(xv.z, xv.w)));
    ((uint2*)xbr)[k4] = make_uint2(p0, p1);
#pragma unroll
    for (int r = 0; r < 16; ++r) {
      const float4 av = ((const float4*)(la + (size_t)r * IN_F))[k4];
      pl[r] = fmaf(xv.x, av.x, pl[r]);
      pl[r] = fmaf(xv.y, av.y, pl[r]);
      pl[r] = fmaf(xv.z, av.z, pl[r]);
      pl[r] = fmaf(xv.w, av.w, pl[r]);
    }
  }
  // reduce across the 16 tk lanes (same tm = 16 consecutive lanes in a wave)
#pragma unroll
  for (int r = 0; r < 16; ++r) {
    float v = pl[r];
#pragma unroll
    for (int d = 8; d > 0; d >>= 1) v += __shfl_xor(v, d);
    pl[r] = v;
  }
  if (tk == 0) {
    float* tp = t + ((size_t)kq * TOKENS + m) * 16;
#pragma unroll
    for (int r = 0; r < 16; ++r) tp[r] = pl[r];
  }
}

// ---------------------------------------------------------------------------
// prep2 (fallback path only): d_out = bias + lora (atomic reduction target).
// ---------------------------------------------------------------------------
__global__ __launch_bounds__(256) void prep2(const float* __restrict__ t,
                                             const float* __restrict__ lb,
                                             const float* __restrict__ bias,
                                             float* __restrict__ out) {
  __shared__ float tS[16 * 16];
  int tid = threadIdx.x;
  int n = blockIdx.x * 256 + tid;
  int mbase = blockIdx.y * 16;
  if (tid < 64) {
    float4 s = make_float4(0.f, 0.f, 0.f, 0.f);
#pragma unroll
    for (int sl = 0; sl < TSLICES; ++sl) {
      float4 a = ((const float4*)(t + (size_t)sl * TOKENS * 16 + (size_t)mbase * 16))[tid];
      s.x += a.x; s.y += a.y; s.z += a.z; s.w += a.w;
    }
    ((float4*)tS)[tid] = s;
  }
  const float4* lbp = (const float4*)(lb + (size_t)n * 16);
  float4 b0 = lbp[0], b1 = lbp[1], b2 = lbp[2], b3 = lbp[3];
  float bv = bias[n];
  __syncthreads();
#pragma unroll
  for (int mm = 0; mm < 16; ++mm) {
    const float* tr = &tS[mm * 16];
    float a = bv;
    a += tr[0] * b0.x + tr[1] * b0.y + tr[2] * b0.z + tr[3] * b0.w;
    a += tr[4] * b1.x + tr[5] * b1.y + tr[6] * b1.z + tr[7] * b1.w;
    a += tr[8] * b2.x + tr[9] * b2.y + tr[10] * b2.z + tr[11] * b2.w;
    a += tr[12] * b3.x + tr[13] * b3.y + tr[14] * b3.z + tr[15] * b3.w;
    out[(size_t)(mbase + mm) * OUT_F + n] = a;
  }
}

// ---------------------------------------------------------------------------
// finish (partial path): out = bias + lora + sum_kz partials. No atomics.
// ---------------------------------------------------------------------------
__global__ __launch_bounds__(256) void finish(const float* __restrict__ t,
                                              const float* __restrict__ lb,
                                              const float* __restrict__ bias,
                                              const float* __restrict__ part,
                                              float* __restrict__ out) {
  __shared__ float tS[16 * 16];
  int tid = threadIdx.x;
  int n = blockIdx.x * 256 + tid;
  int mbase = blockIdx.y * 16;
  if (tid < 64) {
    float4 s = make_float4(0.f, 0.f, 0.f, 0.f);
#pragma unroll
    for (int sl = 0; sl < TSLICES; ++sl) {
      float4 a = ((const float4*)(t + (size_t)sl * TOKENS * 16 + (size_t)mbase * 16))[tid];
      s.x += a.x; s.y += a.y; s.z += a.z; s.w += a.w;
    }
    ((float4*)tS)[tid] = s;
  }
  const float4* lbp = (const float4*)(lb + (size_t)n * 16);
  float4 b0 = lbp[0], b1 = lbp[1], b2 = lbp[2], b3 = lbp[3];
  float bv = bias[n];
  __syncthreads();
#pragma unroll
  for (int mm = 0; mm < 16; ++mm) {
    const float* tr = &tS[mm * 16];
    float a = bv;
    a += tr[0] * b0.x + tr[1] * b0.y + tr[2] * b0.z + tr[3] * b0.w;
    a += tr[4] * b1.x + tr[5] * b1.y + tr[6] * b1.z + tr[7] * b1.w;
    a += tr[8] * b2.x + tr[9] * b2.y + tr[10] * b2.z + tr[11] * b2.w;
    a += tr[12] * b3.x + tr[13] * b3.y + tr[14] * b3.z + tr[15] * b3.w;
    size_t base = (size_t)(mbase + mm) * OUT_F + n;
#pragma unroll
    for (int kz = 0; kz < SPLITK; ++kz)
      a += part[(size_t)kz * TOKENS * OUT_F + base];
    out[base] = a;
  }
}

// ---------------------------------------------------------------------------
// gemm_q2: fused 2-bit-dequant f16 MFMA GEMM, split-K=4, DEPTH-2 pipeline.
// R8 (theory: fixed per-iter latency stall, ~4600 cyc/iter independent of
// waves & LDS traffic in R0-R2): loads for tile kt are now issued at iter
// kt-2 and waited with a COUNTED s_waitcnt vmcnt(7) (T4) -- never drained
// to 0 in the loop. Slack = 2 full iterations (~3500 cyc) > loaded HBM
// latency. Per iter exactly 7 vmem ops (4 A-DMA + 2 B-code + 1 norm),
// pinned between sched_barrier(0) fences so the count is exact; uniform at
// the tail via clamped dummy issues. A: 3-buffer LDS ring (global_load_lds,
// swizzled source). B codes+norm: 2 register sets (X/Y), loop unrolled by 2
// for static names (rule #20). LDS 66 KiB -> 2 blocks/CU.
// ---------------------------------------------------------------------------
__global__ __launch_bounds__(256, 2) void gemm_q2(const u16* __restrict__ xb,
                                                  const int* __restrict__ wq,
                                                  const __half* __restrict__ wn,
                                                  float* __restrict__ dst,
                                                  int mode) {
  __shared__ __align__(16) u16 As0[128 * 64];  // 16 KiB each, DMA ring
  __shared__ __align__(16) u16 As1[128 * 64];
  __shared__ __align__(16) u16 As2[128 * 64];
  __shared__ __align__(16) u16 Bs[128 * 64];   // 16 KiB, dequant target
  __shared__ uint2 lut[256];

  int tid = threadIdx.x;
  int n0 = blockIdx.x * 128;
  int m0 = blockIdx.y * 128;
  int kz = blockIdx.z;
  int kbase = kz * KSPAN;

  {  // dequant LUT: byte -> 4 f16 unit values {-1,-1/3,1/3,1}
    int b = tid;
    float v0 = (float)(b & 3) * (2.f / 3.f) - 1.f;
    float v1 = (float)((b >> 2) & 3) * (2.f / 3.f) - 1.f;
    float v2 = (float)((b >> 4) & 3) * (2.f / 3.f) - 1.f;
    float v3 = (float)((b >> 6) & 3) * (2.f / 3.f) - 1.f;
    u32 lo = __builtin_bit_cast(u32, __float22half2_rn(make_float2(v0, v1)));
    u32 hi = __builtin_bit_cast(u32, __float22half2_rn(make_float2(v2, v3)));
    lut[b] = make_uint2(lo, hi);
  }

  int wave = tid >> 6, lane = tid & 63;
  int quad = lane >> 4, l15 = lane & 15;
  int mo = (wave & 1) * 64, no = (wave >> 1) * 64;

  // A staging: 1024 16B-chunks, 4 per thread, slot = tid + i*256 (lane-linear
  // as global_load_lds requires). Source column is the swizzled one.
  int aslot[4];
  const u16* ag[4];
#pragma unroll
  for (int i = 0; i < 4; ++i) {
    int s = tid + i * 256;
    int mm = s >> 3, c = s & 7;
    int cl = c ^ (mm & 7);
    aslot[i] = s;
    ag[i] = xb + (size_t)(m0 + mm) * IN_F + kbase + cl * 8;
  }

  // B staging: thread -> (row n, half h): 32 consecutive k (32 bytes).
  int bn = tid >> 1, h = tid & 1;
  const char* gB = (const char*)wq + (size_t)(n0 + bn) * IN_F + kbase + h * 32;
  const __half* wnp = wn + (size_t)(n0 + bn) * 64 + kz * (KSPAN / 128);

  f32x4 zero4 = {0.f, 0.f, 0.f, 0.f};
  f32x4 acc[4][4];
#pragma unroll
  for (int i = 0; i < 4; ++i)
#pragma unroll
    for (int j = 0; j < 4; ++j) acc[i][j] = zero4;

  u16* r0 = As0;  // tile kt lives here
  u16* r1 = As1;  // tile kt+1
  u16* r2 = As2;  // DMA target for tile kt+2

  // B code regs: 2 sets (X even iters, Y odd), each reloaded right after use.
  int4 pbX0, pbX1, pbY0, pbY1;
  __half pnX, pnY;

  // ---- prologue: issue L(0) then L(1), each a 7-op group ----
  __builtin_amdgcn_sched_barrier(0);
#pragma unroll
  for (int i = 0; i < 4; ++i) GLOAD16(ag[i], &((uint4*)r0)[aslot[i]]);
  pbX0 = *(const int4*)(gB);
  pbX1 = *(const int4*)(gB + 16);
  pnX = wnp[0];
  __builtin_amdgcn_sched_barrier(0);
#pragma unroll
  for (int i = 0; i < 4; ++i) GLOAD16(ag[i] + 64, &((uint4*)r1)[aslot[i]]);
  pbY0 = *(const int4*)(gB + 64);
  pbY1 = *(const int4*)(gB + 80);
  pnY = wnp[0];
  __builtin_amdgcn_sched_barrier(0);
  // drain LUT ds_writes before any wave can read it after the first barrier
  asm volatile("s_waitcnt lgkmcnt(0)" ::: "memory");

  // One iteration body. KTV = tile index; PB*/PN = this iter's code regs
  // (reloaded for KTV+2 after use); RCUR = LDS buffer of tile KTV; RDMA =
  // ring buffer receiving tile KTV+2.
#define BODY(KTV, PB0, PB1, PN, RCUR, RDMA)                                    \
  do {                                                                         \
    asm volatile("s_waitcnt vmcnt(7)" ::: "memory");                           \
    __builtin_amdgcn_s_barrier();                                              \
    asm volatile("" ::: "memory");                                             \
    __builtin_amdgcn_sched_barrier(0);                                         \
    { /* dequant codes(KTV) -> Bs */                                           \
      __half2 nh = __half2half2(PN);                                           \
      int vv[8] = {PB0.x, PB0.y, PB0.z, PB0.w, PB1.x, PB1.y, PB1.z, PB1.w};    \
      u32 uu[16];                                                              \
      _Pragma("unroll") for (int e = 0; e < 8; ++e) {                          \
        uint2 lv = lut[vv[e] & 255];                                           \
        uu[2 * e] = hm2(lv.x, nh);                                             \
        uu[2 * e + 1] = hm2(lv.y, nh);                                         \
      }                                                                        \
      uint4* Bw = (uint4*)Bs;                                                  \
      _Pragma("unroll") for (int cc = 0; cc < 4; ++cc) {                       \
        int pc = (h * 4 + cc) ^ (bn & 7);                                      \
        Bw[bn * 8 + pc] =                                                      \
            make_uint4(uu[4 * cc], uu[4 * cc + 1], uu[4 * cc + 2], uu[4 * cc + 3]); \
      }                                                                        \
    }                                                                          \
    __builtin_amdgcn_sched_barrier(0);                                         \
    { /* issue L(KTV+2): exactly 7 vmem ops (dummies at tail keep count) */    \
      int kn = (KTV) + 2;                                                      \
      if (kn >= KT) kn = 0;                                                    \
      int ko = kn * 64;                                                        \
      GLOAD16(ag[0] + ko, &((uint4*)RDMA)[aslot[0]]);                          \
      GLOAD16(ag[1] + ko, &((uint4*)RDMA)[aslot[1]]);                          \
      GLOAD16(ag[2] + ko, &((uint4*)RDMA)[aslot[2]]);                          \
      GLOAD16(ag[3] + ko, &((uint4*)RDMA)[aslot[3]]);                          \
      PB0 = *(const int4*)(gB + ko);                                           \
      PB1 = *(const int4*)(gB + ko + 16);                                      \
      PN = wnp[kn >> 1];                                                       \
    }                                                                          \
    __builtin_amdgcn_sched_barrier(0);                                         \
    asm volatile("s_waitcnt lgkmcnt(0)" ::: "memory");                         \
    __builtin_amdgcn_s_barrier();                                              \
    asm volatile("" ::: "memory");                                             \
    __builtin_amdgcn_sched_barrier(0);                                         \
    { /* compute tile KTV: 2 k-substeps x (4+4 frags, 16 MFMAs) */             \
      const uint4* Ar = (const uint4*)(RCUR);                                  \
      _Pragma("unroll") for (int ks = 0; ks < 2; ++ks) {                       \
        f16x8 af[4], bf[4];                                                    \
        _Pragma("unroll") for (int mt = 0; mt < 4; ++mt) {                     \
          int row = mo + mt * 16 + l15;                                        \
          int pc = (ks * 4 + quad) ^ (row & 7);                                \
          af[mt] = __builtin_bit_cast(f16x8, Ar[row * 8 + pc]);                \
        }                                                                      \
        _Pragma("unroll") for (int nt = 0; nt < 4; ++nt) {                     \
          int row = no + nt * 16 + l15;                                        \
          int pc = (ks * 4 + quad) ^ (row & 7);                                \
          bf[nt] = __builtin_bit_cast(f16x8, ((const uint4*)Bs)[row * 8 + pc]);\
        }                                                                      \
        _Pragma("unroll") for (int mt = 0; mt < 4; ++mt)                       \
            _Pragma("unroll") for (int nt = 0; nt < 4; ++nt)                   \
                acc[mt][nt] = __builtin_amdgcn_mfma_f32_16x16x32_f16(          \
                    af[mt], bf[nt], acc[mt][nt], 0, 0, 0);                     \
      }                                                                        \
    }                                                                          \
  } while (0)

#pragma unroll 1
  for (int p = 0; p < KT / 2; ++p) {
    int kt = 2 * p;
    BODY(kt, pbX0, pbX1, pnX, r0, r2);
    { u16* tmp = r0; r0 = r1; r1 = r2; r2 = tmp; }
    BODY(kt + 1, pbY0, pbY1, pnY, r0, r2);
    { u16* tmp = r0; r0 = r1; r1 = r2; r2 = tmp; }
  }
#undef BODY

  // ---- epilogue ----
  // C/D layout: row m = quad*4 + reg, col n = lane&15  [m89/m91 verified]
  if (mode) {
    float* pp = dst + (size_t)kz * TOKENS * OUT_F;
#pragma unroll
    for (int mt = 0; mt < 4; ++mt)
#pragma unroll
      for (int nt = 0; nt < 4; ++nt)
#pragma unroll
        for (int r = 0; r < 4; ++r) {
          int mm = m0 + mo + mt * 16 + quad * 4 + r;
          int nn = n0 + no + nt * 16 + l15;
          pp[(size_t)mm * OUT_F + nn] = acc[mt][nt][r];
        }
  } else {
#pragma unroll
    for (int mt = 0; mt < 4; ++mt)
#pragma unroll
      for (int nt = 0; nt < 4; ++nt)
#pragma unroll
        for (int r = 0; r < 4; ++r) {
          int mm = m0 + mo + mt * 16 + quad * 4 + r;
          int nn = n0 + no + nt * 16 + l15;
          atomicAdd(&dst[(size_t)mm * OUT_F + nn], acc[mt][nt][r]);
        }
  }
}

extern "C" void kernel_launch(void* const* d_in, const int* in_sizes, int n_in,
                              void* d_out, int out_size, void* d_ws, size_t ws_size,
                              hipStream_t stream) {
  (void)in_sizes; (void)n_in; (void)out_size;
  const float* x = (const float*)d_in[0];
  const int* wq = (const int*)d_in[1];
  const void* wn_raw = d_in[2];
  const float* bias = (const float*)d_in[3];
  const float* la = (const float*)d_in[4];
  const float* lb = (const float*)d_in[5];
  float* out = (float*)d_out;

  u16* xb = (u16*)((char*)d_ws + XB_OFF);
  float* t = (float*)((char*)d_ws + T_OFF);
  __half* nf = (__half*)((char*)d_ws + NF_OFF);
  float* part = (float*)((char*)d_ws + PART_OFF);
  int usep = ws_size >= WS_NEED;  // constant per deployment -> graph-safe

  prep<<<640, 256, 0, stream>>>(wn_raw, nf, x, la, xb, t);
  if (usep) {
    gemm_q2<<<dim3(OUT_F / 128, TOKENS / 128, SPLITK), 256, 0, stream>>>(xb, wq, nf, part, 1);
    finish<<<dim3(OUT_F / 256, TOKENS / 16), 256, 0, stream>>>(t, lb, bias, part, out);
  } else {
    prep2<<<dim3(OUT_F / 256, TOKENS / 16), 256, 0, stream>>>(t, lb, bias, out);
    gemm_q2<<<dim3(OUT_F / 128, TOKENS / 128, SPLITK), 256, 0, stream>>>(xb, wq, nf, out, 0);
  }
}

// Round 4
// 175.965 us; speedup vs baseline: 1.0903x; 1.0903x over previous
//
#include <hip/hip_runtime.h>
#include <hip/hip_fp16.h>

typedef unsigned int u32;
typedef unsigned short u16;
typedef _Float16 f16x8 __attribute__((ext_vector_type(8)));
typedef float f32x4 __attribute__((ext_vector_type(4)));

#define OUT_F 8192
#define IN_F 8192
#define TOKENS 256
#define N_GROUPS 524288
#define SPLITK 4
#define KSPAN (IN_F / SPLITK)   // 2048 weights (== bytes of wq per row-split)
#define KT (KSPAN / 64)         // 32 K-iterations

// workspace layout
#define XB_OFF 0
#define T_OFF ((size_t)TOKENS * IN_F * 2)                 // 4 MiB
#define NF_OFF (T_OFF + 65536)
#define PART_OFF (NF_OFF + (size_t)N_GROUPS * 2)          // +1 MiB
#define PART_BYTES ((size_t)SPLITK * TOKENS * OUT_F * 4)  // 32 MiB
#define WS_NEED (PART_OFF + PART_BYTES)

// direct global -> LDS DMA, 16B per lane. LDS dest must be lane-linear
// (wave-uniform base + lane*16); swizzle lives on the GLOBAL source address.
#define GLOAD16(g, l)                                                        \
  __builtin_amdgcn_global_load_lds(                                          \
      (const __attribute__((address_space(1))) void*)(g),                    \
      (__attribute__((address_space(3))) void*)(l), 16, 0, 0)

// packed f16 multiply on bit-pattern: 4 weights dequant = 1 LUT read + 2 of these
__device__ __forceinline__ u32 hm2(u32 a, __half2 s) {
  return __builtin_bit_cast(u32, __hmul2(__builtin_bit_cast(__half2, a), s));
}

// ---------------------------------------------------------------------------
// prep: fused normcvt + prep1 (R0 version, reverted: R3's k-slicing attacked
// L2-resident la traffic -- a non-problem -- and cost ~24 us via a 128-block
// grid).
// ---------------------------------------------------------------------------
__global__ __launch_bounds__(256) void prep(const void* __restrict__ wn,
                                            __half* __restrict__ nf,
                                            const float* __restrict__ x,
                                            const float* __restrict__ la,
                                            u16* __restrict__ xb,
                                            float* __restrict__ t) {
  int tid = threadIdx.x;
  if (blockIdx.x < 512) {
    __shared__ int votes[3];
    if (tid < 3) votes[tid] = 0;
    __syncthreads();
    const u16* pu = (const u16*)wn;
    const u32* pw = (const u32*)wn;
    int v16 = 0, vbf = 0, vf = 0;
    for (int i = tid; i < 2048; i += 256) {
      u16 u = pu[i];
      float h = __half2float(__builtin_bit_cast(__half, u));
      float b = __builtin_bit_cast(float, ((u32)u) << 16);
      if (h > 0.008f && h < 1.002f) v16++;
      if (b > 0.008f && b < 1.002f) vbf++;
    }
    for (int i = tid; i < 1024; i += 256) {
      float f = __builtin_bit_cast(float, pw[i]);
      if (f > 0.008f && f < 1.002f) vf++;
    }
    atomicAdd(&votes[0], v16);
    atomicAdd(&votes[1], vbf);
    atomicAdd(&votes[2], vf);
    __syncthreads();
    int a16 = votes[0], abf = votes[1], af32 = 2 * votes[2];
    int mode = (a16 >= abf && a16 >= af32) ? 0 : (abf >= af32 ? 1 : 2);
#pragma unroll
    for (int i = 0; i < 4; ++i) {
      int g = blockIdx.x * 1024 + i * 256 + tid;
      float v;
      if (mode == 0) v = __half2float(((const __half*)wn)[g]);
      else if (mode == 1) v = __builtin_bit_cast(float, ((u32)((const u16*)wn)[g]) << 16);
      else v = ((const float*)wn)[g];
      nf[g] = __float2half(v);
    }
    return;
  }
  int b2 = blockIdx.x - 512;
  int m = b2 & 255;
  int half = b2 >> 8;
  const float4* xr = (const float4*)(x + (size_t)m * IN_F);
  u32* xbr = (u32*)(xb + (size_t)m * IN_F);
  float pl[16];
#pragma unroll
  for (int r = 0; r < 16; ++r) pl[r] = 0.f;
#pragma unroll
  for (int it = 0; it < 4; ++it) {
    int k4 = half * 1024 + it * 256 + tid;
    float4 xv = xr[k4];
    u32 p0 = __builtin_bit_cast(u32, __float22half2_rn(make_float2(xv.x, xv.y)));
    u32 p1 = __builtin_bit_cast(u32, __float22half2_rn(make_float2(xv.z, xv.w)));
    ((uint2*)xbr)[k4] = make_uint2(p0, p1);
#pragma unroll
    for (int r = 0; r < 16; ++r) {
      const float4 av = ((const float4*)(la + (size_t)r * IN_F))[k4];
      pl[r] = fmaf(xv.x, av.x, pl[r]);
      pl[r] = fmaf(xv.y, av.y, pl[r]);
      pl[r] = fmaf(xv.z, av.z, pl[r]);
      pl[r] = fmaf(xv.w, av.w, pl[r]);
    }
  }
#pragma unroll
  for (int r = 0; r < 16; ++r) {
    float v = pl[r];
#pragma unroll
    for (int d = 32; d > 0; d >>= 1) v += __shfl_xor(v, d);
    pl[r] = v;
  }
  __shared__ float red[4][16];
  int wave = tid >> 6, lane = tid & 63;
  if (lane == 0) {
#pragma unroll
    for (int r = 0; r < 16; ++r) red[wave][r] = pl[r];
  }
  __syncthreads();
  if (tid < 16)
    t[((size_t)half * TOKENS + m) * 16 + tid] =
        red[0][tid] + red[1][tid] + red[2][tid] + red[3][tid];
}

// ---------------------------------------------------------------------------
// prep2 (fallback path only): d_out = bias + lora (atomic reduction target).
// ---------------------------------------------------------------------------
__global__ __launch_bounds__(256) void prep2(const float* __restrict__ t,
                                             const float* __restrict__ lb,
                                             const float* __restrict__ bias,
                                             float* __restrict__ out) {
  __shared__ float tS[16 * 16];
  int tid = threadIdx.x;
  int n = blockIdx.x * 256 + tid;
  int mbase = blockIdx.y * 16;
  if (tid < 64) {
    float4 a = ((const float4*)(t + (size_t)mbase * 16))[tid];
    float4 b = ((const float4*)(t + (size_t)TOKENS * 16 + (size_t)mbase * 16))[tid];
    ((float4*)tS)[tid] = make_float4(a.x + b.x, a.y + b.y, a.z + b.z, a.w + b.w);
  }
  const float4* lbp = (const float4*)(lb + (size_t)n * 16);
  float4 b0 = lbp[0], b1 = lbp[1], b2 = lbp[2], b3 = lbp[3];
  float bv = bias[n];
  __syncthreads();
#pragma unroll
  for (int mm = 0; mm < 16; ++mm) {
    const float* tr = &tS[mm * 16];
    float a = bv;
    a += tr[0] * b0.x + tr[1] * b0.y + tr[2] * b0.z + tr[3] * b0.w;
    a += tr[4] * b1.x + tr[5] * b1.y + tr[6] * b1.z + tr[7] * b1.w;
    a += tr[8] * b2.x + tr[9] * b2.y + tr[10] * b2.z + tr[11] * b2.w;
    a += tr[12] * b3.x + tr[13] * b3.y + tr[14] * b3.z + tr[15] * b3.w;
    out[(size_t)(mbase + mm) * OUT_F + n] = a;
  }
}

// ---------------------------------------------------------------------------
// finish (partial path): out = bias + lora + sum_kz partials. No atomics.
// ---------------------------------------------------------------------------
__global__ __launch_bounds__(256) void finish(const float* __restrict__ t,
                                              const float* __restrict__ lb,
                                              const float* __restrict__ bias,
                                              const float* __restrict__ part,
                                              float* __restrict__ out) {
  __shared__ float tS[16 * 16];
  int tid = threadIdx.x;
  int n = blockIdx.x * 256 + tid;
  int mbase = blockIdx.y * 16;
  if (tid < 64) {
    float4 a = ((const float4*)(t + (size_t)mbase * 16))[tid];
    float4 b = ((const float4*)(t + (size_t)TOKENS * 16 + (size_t)mbase * 16))[tid];
    ((float4*)tS)[tid] = make_float4(a.x + b.x, a.y + b.y, a.z + b.z, a.w + b.w);
  }
  const float4* lbp = (const float4*)(lb + (size_t)n * 16);
  float4 b0 = lbp[0], b1 = lbp[1], b2 = lbp[2], b3 = lbp[3];
  float bv = bias[n];
  __syncthreads();
#pragma unroll
  for (int mm = 0; mm < 16; ++mm) {
    const float* tr = &tS[mm * 16];
    float a = bv;
    a += tr[0] * b0.x + tr[1] * b0.y + tr[2] * b0.z + tr[3] * b0.w;
    a += tr[4] * b1.x + tr[5] * b1.y + tr[6] * b1.z + tr[7] * b1.w;
    a += tr[8] * b2.x + tr[9] * b2.y + tr[10] * b2.z + tr[11] * b2.w;
    a += tr[12] * b3.x + tr[13] * b3.y + tr[14] * b3.z + tr[15] * b3.w;
    size_t base = (size_t)(mbase + mm) * OUT_F + n;
#pragma unroll
    for (int kz = 0; kz < SPLITK; ++kz)
      a += part[(size_t)kz * TOKENS * OUT_F + base];
    out[base] = a;
  }
}

// ---------------------------------------------------------------------------
// gemm_q2: fused 2-bit-dequant f16 MFMA GEMM, split-K=4, SINGLE-BARRIER
// fused-phase iteration.
// R9 theory: R0/R1/R3 all pinned at ~2280 cyc/block-iter with phase-
// serialized [barrier; dequant; barrier; compute] -- each phase's latency
// chain (LUT gather ~120cy, frag read ~120cy, MFMA deps) is exposed since
// all waves of a block are in the same phase. Fix: ONE barrier-free region
// per iter containing independent work the scheduler can interleave:
//   issue A-DMA(kt+1)->As[cur^1], codes(kt+2)->regs   (VMEM)
//   dequant codes(kt+1) -> Bs[cur^1]                  (VALU + LUT + ds_write)
//   compute(kt) from As[cur]/Bs[cur]                  (ds_read + MFMA)
//   __syncthreads()                                   (single barrier)
// Loads drain at END of the iter they were issued in (full-iter slack).
// setprio(1) around the MFMA cluster (T5: phase-diverse waves now exist).
// X/Y static code-reg sets, unroll-2 (rule #20). LDS 66 KiB -> 2 blocks/CU.
// ---------------------------------------------------------------------------
__global__ __launch_bounds__(256, 2) void gemm_q2(const u16* __restrict__ xb,
                                                  const int* __restrict__ wq,
                                                  const __half* __restrict__ wn,
                                                  float* __restrict__ dst,
                                                  int mode) {
  __shared__ __align__(16) u16 As[2][128 * 64];  // 2 x 16 KiB, DMA-filled
  __shared__ __align__(16) u16 Bs[2][128 * 64];  // 2 x 16 KiB, dequant target
  __shared__ uint2 lut[256];

  int tid = threadIdx.x;
  int n0 = blockIdx.x * 128;
  int m0 = blockIdx.y * 128;
  int kz = blockIdx.z;
  int kbase = kz * KSPAN;

  {  // dequant LUT: byte -> 4 f16 unit values {-1,-1/3,1/3,1}
    int b = tid;
    float v0 = (float)(b & 3) * (2.f / 3.f) - 1.f;
    float v1 = (float)((b >> 2) & 3) * (2.f / 3.f) - 1.f;
    float v2 = (float)((b >> 4) & 3) * (2.f / 3.f) - 1.f;
    float v3 = (float)((b >> 6) & 3) * (2.f / 3.f) - 1.f;
    u32 lo = __builtin_bit_cast(u32, __float22half2_rn(make_float2(v0, v1)));
    u32 hi = __builtin_bit_cast(u32, __float22half2_rn(make_float2(v2, v3)));
    lut[b] = make_uint2(lo, hi);
  }

  int wave = tid >> 6, lane = tid & 63;
  int quad = lane >> 4, l15 = lane & 15;
  int mo = (wave & 1) * 64, no = (wave >> 1) * 64;

  // A staging: 1024 16B-chunks, 4 per thread, slot = tid + i*256 (lane-linear
  // as global_load_lds requires). Source column is the swizzled one.
  int aslot[4];
  const u16* ag[4];
#pragma unroll
  for (int i = 0; i < 4; ++i) {
    int s = tid + i * 256;
    int mm = s >> 3, c = s & 7;
    int cl = c ^ (mm & 7);
    aslot[i] = s;
    ag[i] = xb + (size_t)(m0 + mm) * IN_F + kbase + cl * 8;
  }

  // B staging: thread -> (row n, half h): 32 consecutive k (32 bytes).
  // wq byte address == flat weight index (each int32 = 1 code byte = 4 wts).
  int bn = tid >> 1, h = tid & 1;
  const char* gB = (const char*)wq + (size_t)(n0 + bn) * IN_F + kbase + h * 32;
  const __half* wnp = wn + (size_t)(n0 + bn) * 64 + kz * (KSPAN / 128);

  f32x4 zero4 = {0.f, 0.f, 0.f, 0.f};
  f32x4 acc[4][4];
#pragma unroll
  for (int i = 0; i < 4; ++i)
#pragma unroll
    for (int j = 0; j < 4; ++j) acc[i][j] = zero4;

  // dequant codes -> Bs[BUF] (swizzled f16 tile)
#define DEQ(PB0, PB1, PN, BUF)                                                 \
  {                                                                            \
    __half2 nh = __half2half2(PN);                                             \
    int vv[8] = {PB0.x, PB0.y, PB0.z, PB0.w, PB1.x, PB1.y, PB1.z, PB1.w};      \
    u32 uu[16];                                                                \
    _Pragma("unroll") for (int e = 0; e < 8; ++e) {                            \
      uint2 lv = lut[vv[e] & 255];                                             \
      uu[2 * e] = hm2(lv.x, nh);                                               \
      uu[2 * e + 1] = hm2(lv.y, nh);                                           \
    }                                                                          \
    uint4* Bw = (uint4*)Bs[BUF];                                               \
    _Pragma("unroll") for (int cc = 0; cc < 4; ++cc) {                         \
      int pc = (h * 4 + cc) ^ (bn & 7);                                        \
      Bw[bn * 8 + pc] =                                                        \
          make_uint4(uu[4 * cc], uu[4 * cc + 1], uu[4 * cc + 2], uu[4 * cc + 3]); \
    }                                                                          \
  }

  int4 pbX0, pbX1, pbY0, pbY1;
  __half pnX, pnY;

  // ---- prologue ----
  // A(0) -> As[0]; codes(0) -> X
#pragma unroll
  for (int i = 0; i < 4; ++i) GLOAD16(ag[i], &((uint4*)As[0])[aslot[i]]);
  pbX0 = *(const int4*)(gB);
  pbX1 = *(const int4*)(gB + 16);
  pnX = wnp[0];
  __syncthreads();  // LUT visible; A(0) landed; codes(0) in regs
  DEQ(pbX0, pbX1, pnX, 0);  // B(0) -> Bs[0]
  pbY0 = *(const int4*)(gB + 64);  // codes(1) -> Y
  pbY1 = *(const int4*)(gB + 80);
  pnY = wnp[0];
  __syncthreads();  // Bs[0] visible

  // One iteration. CUR = kt&1 (compile-time). D* = dequant set (codes kt+1),
  // L* = load target set (codes kt+2).
#define BODY(KTV, CUR, DB0, DB1, DN, LB0, LB1, LN)                             \
  do {                                                                         \
    int kn1 = (KTV) + 1; if (kn1 >= KT) kn1 = 0;                               \
    int kn2 = (KTV) + 2; if (kn2 >= KT) kn2 = 0;                               \
    int ko1 = kn1 * 64, ko2 = kn2 * 64;                                        \
    GLOAD16(ag[0] + ko1, &((uint4*)As[(CUR) ^ 1])[aslot[0]]);                  \
    GLOAD16(ag[1] + ko1, &((uint4*)As[(CUR) ^ 1])[aslot[1]]);                  \
    GLOAD16(ag[2] + ko1, &((uint4*)As[(CUR) ^ 1])[aslot[2]]);                  \
    GLOAD16(ag[3] + ko1, &((uint4*)As[(CUR) ^ 1])[aslot[3]]);                  \
    LB0 = *(const int4*)(gB + ko2);                                            \
    LB1 = *(const int4*)(gB + ko2 + 16);                                       \
    LN = wnp[kn2 >> 1];                                                        \
    DEQ(DB0, DB1, DN, (CUR) ^ 1);                                              \
    {                                                                          \
      const uint4* Ar = (const uint4*)As[CUR];                                 \
      const uint4* Br = (const uint4*)Bs[CUR];                                 \
      _Pragma("unroll") for (int ks = 0; ks < 2; ++ks) {                       \
        f16x8 af[4], bf[4];                                                    \
        _Pragma("unroll") for (int mt = 0; mt < 4; ++mt) {                     \
          int row = mo + mt * 16 + l15;                                        \
          int pc = (ks * 4 + quad) ^ (row & 7);                                \
          af[mt] = __builtin_bit_cast(f16x8, Ar[row * 8 + pc]);                \
        }                                                                      \
        _Pragma("unroll") for (int nt = 0; nt < 4; ++nt) {                     \
          int row = no + nt * 16 + l15;                                        \
          int pc = (ks * 4 + quad) ^ (row & 7);                                \
          bf[nt] = __builtin_bit_cast(f16x8, Br[row * 8 + pc]);                \
        }                                                                      \
        __builtin_amdgcn_s_setprio(1);                                         \
        _Pragma("unroll") for (int mt = 0; mt < 4; ++mt)                       \
            _Pragma("unroll") for (int nt = 0; nt < 4; ++nt)                   \
                acc[mt][nt] = __builtin_amdgcn_mfma_f32_16x16x32_f16(          \
                    af[mt], bf[nt], acc[mt][nt], 0, 0, 0);                     \
        __builtin_amdgcn_s_setprio(0);                                         \
      }                                                                        \
    }                                                                          \
    __syncthreads();                                                           \
  } while (0)

#pragma unroll 1
  for (int p = 0; p < KT / 2; ++p) {
    int kt = 2 * p;
    BODY(kt, 0, pbY0, pbY1, pnY, pbX0, pbX1, pnX);
    BODY(kt + 1, 1, pbX0, pbX1, pnX, pbY0, pbY1, pnY);
  }
#undef BODY
#undef DEQ

  // ---- epilogue ----
  // C/D layout: row m = quad*4 + reg, col n = lane&15  [m89/m91 verified]
  if (mode) {
    float* pp = dst + (size_t)kz * TOKENS * OUT_F;
#pragma unroll
    for (int mt = 0; mt < 4; ++mt)
#pragma unroll
      for (int nt = 0; nt < 4; ++nt)
#pragma unroll
        for (int r = 0; r < 4; ++r) {
          int mm = m0 + mo + mt * 16 + quad * 4 + r;
          int nn = n0 + no + nt * 16 + l15;
          pp[(size_t)mm * OUT_F + nn] = acc[mt][nt][r];
        }
  } else {
#pragma unroll
    for (int mt = 0; mt < 4; ++mt)
#pragma unroll
      for (int nt = 0; nt < 4; ++nt)
#pragma unroll
        for (int r = 0; r < 4; ++r) {
          int mm = m0 + mo + mt * 16 + quad * 4 + r;
          int nn = n0 + no + nt * 16 + l15;
          atomicAdd(&dst[(size_t)mm * OUT_F + nn], acc[mt][nt][r]);
        }
  }
}

extern "C" void kernel_launch(void* const* d_in, const int* in_sizes, int n_in,
                              void* d_out, int out_size, void* d_ws, size_t ws_size,
                              hipStream_t stream) {
  (void)in_sizes; (void)n_in; (void)out_size;
  const float* x = (const float*)d_in[0];
  const int* wq = (const int*)d_in[1];
  const void* wn_raw = d_in[2];
  const float* bias = (const float*)d_in[3];
  const float* la = (const float*)d_in[4];
  const float* lb = (const float*)d_in[5];
  float* out = (float*)d_out;

  u16* xb = (u16*)((char*)d_ws + XB_OFF);
  float* t = (float*)((char*)d_ws + T_OFF);
  __half* nf = (__half*)((char*)d_ws + NF_OFF);
  float* part = (float*)((char*)d_ws + PART_OFF);
  int usep = ws_size >= WS_NEED;  // constant per deployment -> graph-safe

  prep<<<1024, 256, 0, stream>>>(wn_raw, nf, x, la, xb, t);
  if (usep) {
    gemm_q2<<<dim3(OUT_F / 128, TOKENS / 128, SPLITK), 256, 0, stream>>>(xb, wq, nf, part, 1);
    finish<<<dim3(OUT_F / 256, TOKENS / 16), 256, 0, stream>>>(t, lb, bias, part, out);
  } else {
    prep2<<<dim3(OUT_F / 256, TOKENS / 16), 256, 0, stream>>>(t, lb, bias, out);
    gemm_q2<<<dim3(OUT_F / 128, TOKENS / 128, SPLITK), 256, 0, stream>>>(xb, wq, nf, out, 0);
  }
}